// Round 5
// baseline (165.338 us; speedup 1.0000x reference)
//
#include <hip/hip_runtime.h>
#include <hip/hip_fp16.h>
#include <math.h>

#define N_MESH   5151
#define NB       8
#define TT       2048
#define HID      256
#define NLAYERS  3
#define NCHUNK   16
#define CHUNK    128           // TT / NCHUNK
#define TSTR     128           // table row stride (ushort) -- pow2, linear build
#define NPAD     6144          // padded mesh count (6 blocks * 1024)
#define NBLK1    6             // phase1 n-blocks (1024 pts each, 4/thread)
#define NBLK3    6             // phase3 n-blocks
#define SCAN1_GRID (NBLK1 * NB * NCHUNK)   // 768
#define MLP_ROWS 16
#define MLP_NBLK 322           // ceil(5151/16)

// ws layout (floats)  -- total 2365440 floats = 9.46 MB
#define WS_DENSITY 0           // 5151
#define WS_SUM     5184        // 1
#define WS_PART    6144        // NB*NBLK3*8*TT = 786432 -> ends 792576
#define WS_P       792576      // NCHUNK*NB*NPAD = 786432 -> ends 1579008
#define WS_Q       1579008     // 786432 -> ends 2365440

// out layout (floats)
#define OUT_BNORM  0           // 16384
#define OUT_DENSB  16384       // 41208
#define OUT_M      57592       // 16384
#define OUT_S0     73976       // 41208
#define OUT_MESHB  115184      // 82416

__device__ __forceinline__ float sigmoid_fast(float x) {
    float e = __expf(-x);
    return __builtin_amdgcn_rcpf(1.0f + e);
}

// Direction-resolved A-table (fp16), linear conflict-free build.
// inc step: A = 1-sigmoid((h-g/100)*1000) = 1/(1+exp(1000h-10g))
// dec step: A = sigmoid(...)              = 1/(1+exp(10g-1000h))
__device__ __forceinline__ void build_table(int tid, const float* hs2,
                                            float* sgv, unsigned short* tab)
{
    if (tid < CHUNK) sgv[tid] = (hs2[tid + 1] >= hs2[tid]) ? 1.0f : -1.0f;
#pragma unroll
    for (int k = 0; k < (CHUNK * TSTR) / 256; ++k) {
        int idx = tid + k * 256;
        int t = idx >> 7, g = idx & 127;
        float ht = hs2[t + 1];
        bool inc = (ht >= hs2[t]);
        float bx = ht * 1000.0f;
        float y = inc ? fmaf(-10.f, (float)g, bx) : fmaf(10.f, (float)g, -bx);
        float A = __builtin_amdgcn_rcpf(1.0f + __expf(y));
        tab[idx] = __half_as_ushort(__float2half(A));
    }
}

// ---------------------------------------------------------------------------
// kernel1: blocks [0,322) = density MLP (long pole, launched first),
//          blocks [322,1090) = scan phase1. Block-uniform branch.
// ---------------------------------------------------------------------------
__global__ __launch_bounds__(256) void k1_mlp_scan1(
    const float* __restrict__ dec, const float* __restrict__ y0,
    const float* __restrict__ mesh, const float* __restrict__ Win,
    const float* __restrict__ bin,  const float* __restrict__ Wblk,
    const float* __restrict__ bblk, const float* __restrict__ Wout,
    const float* __restrict__ bout, float* __restrict__ ws_density,
    float* __restrict__ Pout, float* __restrict__ Qout)
{
    __shared__ __align__(16) char smem[49152];
    const int tid = threadIdx.x;

    if (blockIdx.x < MLP_NBLK) {
        // ------------------ density MLP ------------------
        float* hA = (float*)smem;                    // 16 x 256 (16 KB)
        float* wt = (float*)(smem + 16384);          // 2 x 16 x 256 (32 KB)
        const int row0 = blockIdx.x * MLP_ROWS;
        const int w = tid >> 6;
        const int lane = tid & 63;
        const int c0 = lane * 4;

        // input layer (rows wave-private: r = w*4+j)
        {
            float4 w0 = *(const float4*)&Win[c0];
            float4 w1 = *(const float4*)&Win[HID + c0];
            float4 bi = *(const float4*)&bin[c0];
#pragma unroll
            for (int j = 0; j < 4; ++j) {
                int r = w * 4 + j;
                int gr = row0 + r;
                float m0 = 0.f, m1 = 0.f;
                if (gr < N_MESH) { m0 = mesh[2 * gr]; m1 = mesh[2 * gr + 1]; }
                float4 h;
                h.x = fmaxf(fmaf(m0, w0.x, fmaf(m1, w1.x, bi.x)), 0.f);
                h.y = fmaxf(fmaf(m0, w0.y, fmaf(m1, w1.y, bi.y)), 0.f);
                h.z = fmaxf(fmaf(m0, w0.z, fmaf(m1, w1.z, bi.z)), 0.f);
                h.w = fmaxf(fmaf(m0, w0.w, fmaf(m1, w1.w, bi.w)), 0.f);
                *(float4*)&hA[r * HID + c0] = h;
            }
        }

        // prefetch tile 0 of layer 0 (linear float4: thread covers f, f+256, ...)
        float4 ld[4];
#pragma unroll
        for (int i = 0; i < 4; ++i)
            ld[i] = *(const float4*)&Wblk[(tid + 256 * i) * 4];

        int parity = 0;
        for (int L = 0; L < NLAYERS; ++L) {
            const float* WL = Wblk + (size_t)L * HID * HID;
            float4 acc[4];
#pragma unroll
            for (int j = 0; j < 4; ++j) acc[j] = make_float4(0.f, 0.f, 0.f, 0.f);

            for (int s = 0; s < 16; ++s) {
                float* wd = wt + parity * 4096;
#pragma unroll
                for (int i = 0; i < 4; ++i)
                    *(float4*)&wd[(tid + 256 * i) * 4] = ld[i];  // linear, conflict-free
                __syncthreads();

                // prefetch next tile
                if (s < 15) {
                    const float* Wn = WL + (s + 1) * 16 * HID;
#pragma unroll
                    for (int i = 0; i < 4; ++i)
                        ld[i] = *(const float4*)&Wn[(tid + 256 * i) * 4];
                } else if (L < NLAYERS - 1) {
                    const float* Wn = Wblk + (size_t)(L + 1) * HID * HID;
#pragma unroll
                    for (int i = 0; i < 4; ++i)
                        ld[i] = *(const float4*)&Wn[(tid + 256 * i) * 4];
                }

                int k0 = s * 16;
#pragma unroll
                for (int kk = 0; kk < 16; kk += 4) {
                    float4 wv0 = *(const float4*)&wd[(kk + 0) * HID + c0];
                    float4 wv1 = *(const float4*)&wd[(kk + 1) * HID + c0];
                    float4 wv2 = *(const float4*)&wd[(kk + 2) * HID + c0];
                    float4 wv3 = *(const float4*)&wd[(kk + 3) * HID + c0];
#pragma unroll
                    for (int j = 0; j < 4; ++j) {
                        float4 hr = *(const float4*)&hA[(w * 4 + j) * HID + k0 + kk];
                        acc[j].x = fmaf(hr.x, wv0.x, acc[j].x);
                        acc[j].y = fmaf(hr.x, wv0.y, acc[j].y);
                        acc[j].z = fmaf(hr.x, wv0.z, acc[j].z);
                        acc[j].w = fmaf(hr.x, wv0.w, acc[j].w);
                        acc[j].x = fmaf(hr.y, wv1.x, acc[j].x);
                        acc[j].y = fmaf(hr.y, wv1.y, acc[j].y);
                        acc[j].z = fmaf(hr.y, wv1.z, acc[j].z);
                        acc[j].w = fmaf(hr.y, wv1.w, acc[j].w);
                        acc[j].x = fmaf(hr.z, wv2.x, acc[j].x);
                        acc[j].y = fmaf(hr.z, wv2.y, acc[j].y);
                        acc[j].z = fmaf(hr.z, wv2.z, acc[j].z);
                        acc[j].w = fmaf(hr.z, wv2.w, acc[j].w);
                        acc[j].x = fmaf(hr.w, wv3.x, acc[j].x);
                        acc[j].y = fmaf(hr.w, wv3.y, acc[j].y);
                        acc[j].z = fmaf(hr.w, wv3.z, acc[j].z);
                        acc[j].w = fmaf(hr.w, wv3.w, acc[j].w);
                    }
                }
                parity ^= 1;
            }
            // residual (wave-private rows; no barrier needed)
            float4 bb = *(const float4*)&bblk[L * HID + c0];
#pragma unroll
            for (int j = 0; j < 4; ++j) {
                int r = w * 4 + j;
                float4 h = *(float4*)&hA[r * HID + c0];
                h.x += fmaxf(acc[j].x + bb.x, 0.f);
                h.y += fmaxf(acc[j].y + bb.y, 0.f);
                h.z += fmaxf(acc[j].z + bb.z, 0.f);
                h.w += fmaxf(acc[j].w + bb.w, 0.f);
                *(float4*)&hA[r * HID + c0] = h;
            }
        }

        // output layer + sigmoid
        float4 wo = *(const float4*)&Wout[c0];
        float bo = bout[0];
        float p[4];
#pragma unroll
        for (int j = 0; j < 4; ++j) {
            float4 h = *(const float4*)&hA[(w * 4 + j) * HID + c0];
            p[j] = h.x * wo.x + h.y * wo.y + h.z * wo.z + h.w * wo.w;
        }
#pragma unroll
        for (int st = 1; st < 64; st <<= 1)
#pragma unroll
            for (int j = 0; j < 4; ++j) p[j] += __shfl_xor(p[j], st, 64);
        if (lane == 0) {
#pragma unroll
            for (int j = 0; j < 4; ++j) {
                int gr = row0 + w * 4 + j;
                if (gr < N_MESH) ws_density[gr] = sigmoid_fast(p[j] + bo);
            }
        }
    } else {
        // ------------------ scan phase 1 ------------------
        float* hs2 = (float*)smem;                         // CHUNK+1
        float* sgv = hs2 + 132;                            // CHUNK
        unsigned short* tab = (unsigned short*)(smem + 1056);  // CHUNK*TSTR

        const int sb = blockIdx.x - MLP_NBLK;
        const int nb = sb % NBLK1;
        const int rem = sb / NBLK1;
        const int b = rem & 7;
        const int c = rem >> 3;
        const int t0 = c * CHUNK;

        if (tid < CHUNK) hs2[tid + 1] = dec[b * TT + t0 + tid];
        if (tid == 0) hs2[0] = (c == 0) ? y0[b] : dec[b * TT + t0 - 1];
        __syncthreads();
        build_table(tid, hs2, sgv, tab);
        __syncthreads();

        int ga[4], gb[4];
#pragma unroll
        for (int q = 0; q < 4; ++q) {
            int n = nb * 1024 + q * 256 + tid;
            if (n < N_MESH) {
                gb[q] = (int)(mesh[2 * n]     * 100.0f + 0.5f);
                ga[q] = (int)(mesh[2 * n + 1] * 100.0f + 0.5f);
            } else { ga[q] = 0; gb[q] = 0; }
        }

        float P[4] = {1.f, 1.f, 1.f, 1.f};
        float R[4];
        float gprev = sgv[0];
#pragma unroll
        for (int q = 0; q < 4; ++q) R[q] = -gprev;

        for (int tb = 0; tb < CHUNK; tb += 16) {
#pragma unroll
            for (int j = 0; j < 16; ++j) {
                int t = tb + j;
                float sgt = sgv[t];
                float dl = gprev - sgt;      // 0 or +-2, wave-uniform
                gprev = sgt;
                bool inc = sgt > 0.0f;
                int base = t << 7;
#pragma unroll
                for (int q = 0; q < 4; ++q) {
                    int ig = inc ? ga[q] : gb[q];
                    float A = __half2float(__ushort_as_half(tab[base + ig]));
                    float r = R[q] + dl;
                    P[q] *= A;
                    R[q] = r * A;
                }
            }
        }
        size_t basew = ((size_t)(c * NB + b)) * NPAD;
#pragma unroll
        for (int q = 0; q < 4; ++q) {
            int n = nb * 1024 + q * 256 + tid;
            Pout[basew + n] = P[q];
            Qout[basew + n] = R[q] + gprev;   // Q = R + g_last
        }
    }
}

// ---------------------------------------------------------------------------
// kernel2: phase2 (chunk-boundary states, in-place into P) + density sum.
// ---------------------------------------------------------------------------
__global__ __launch_bounds__(256) void k2_phase2_sum(
    const float* __restrict__ s0_in, float* __restrict__ P,
    const float* __restrict__ Q, const float* __restrict__ density,
    float* __restrict__ sum_out)
{
    const int tid = threadIdx.x;
    if (blockIdx.x == 24) {
        if (blockIdx.y != 0) return;
        __shared__ float red[4];
        float p = 0.f;
        for (int i = tid; i < N_MESH; i += 256) p += density[i];
#pragma unroll
        for (int st = 1; st < 64; st <<= 1) p += __shfl_xor(p, st, 64);
        int lane = tid & 63, w = tid >> 6;
        if (lane == 0) red[w] = p;
        __syncthreads();
        if (tid == 0) sum_out[0] = red[0] + red[1] + red[2] + red[3];
        return;
    }
    const int n = blockIdx.x * 256 + tid;
    const int b = blockIdx.y;
    float s = (n < N_MESH) ? s0_in[b * N_MESH + n] : 0.f;
#pragma unroll
    for (int c = 0; c < NCHUNK; ++c) {
        size_t idx = ((size_t)(c * NB + b)) * NPAD + n;
        float Pv = P[idx], Qv = Q[idx];
        P[idx] = s;
        s = fmaf(Pv, s, Qv);
    }
}

// ---------------------------------------------------------------------------
// kernel3: phase3 replay. z-form: z = (z+dl)*A; m-sign term in finalize.
// ---------------------------------------------------------------------------
__global__ __launch_bounds__(256) void k3_phase3(
    const float* __restrict__ dec, const float* __restrict__ y0,
    const float* __restrict__ mesh, const float* __restrict__ density,
    const float* __restrict__ Sstart, float* __restrict__ partials)
{
    __shared__ __align__(16) char smem[34048];
    float* hs2 = (float*)smem;
    float* sgv = hs2 + 132;
    unsigned short* tab = (unsigned short*)(smem + 1056);

    const int tid = threadIdx.x;
    const int bx = blockIdx.x;
    const int nb = bx % NBLK3;
    const int rem = bx / NBLK3;
    const int b = rem & 7;
    const int c = rem >> 3;
    const int t0 = c * CHUNK;
    const int lane = tid & 63, w = tid >> 6;

    if (tid < CHUNK) hs2[tid + 1] = dec[b * TT + t0 + tid];
    if (tid == 0) hs2[0] = (c == 0) ? y0[b] : dec[b * TT + t0 - 1];
    __syncthreads();
    build_table(tid, hs2, sgv, tab);
    __syncthreads();

    int ga[4], gb[4];
    float d[4], z[4];
    float gprev = sgv[0];
#pragma unroll
    for (int q = 0; q < 4; ++q) {
        int n = nb * 1024 + q * 256 + tid;
        float S = 0.f;
        if (n < N_MESH) {
            gb[q] = (int)(mesh[2 * n]     * 100.0f + 0.5f);
            ga[q] = (int)(mesh[2 * n + 1] * 100.0f + 0.5f);
            d[q]  = density[n];
            S = Sstart[((size_t)(c * NB + b)) * NPAD + n];
        } else { ga[q] = 0; gb[q] = 0; d[q] = 0.f; }
        z[q] = S - gprev;
    }

    float* pout = partials +
        ((size_t)((b * NBLK3 + nb) * 8 + w * 2 + (lane >> 5))) * TT + t0;

    for (int tb = 0; tb < CHUNK; tb += 16) {
        float v[16];
#pragma unroll
        for (int j = 0; j < 16; ++j) {
            int t = tb + j;
            float sgt = sgv[t];
            float dl = gprev - sgt;
            gprev = sgt;
            bool inc = sgt > 0.0f;
            int base = t << 7;
            float a0, a1;
#pragma unroll
            for (int q = 0; q < 4; ++q) {
                int ig = inc ? ga[q] : gb[q];
                float A = __half2float(__ushort_as_half(tab[base + ig]));
                z[q] = (z[q] + dl) * A;
            }
            a0 = d[0] * z[0];
            a1 = d[1] * z[1];
            a0 = fmaf(d[2], z[2], a0);
            a1 = fmaf(d[3], z[3], a1);
            v[j] = a0 + a1;
        }
#pragma unroll
        for (int st = 1; st < 32; st <<= 1) {
#pragma unroll
            for (int j = 0; j < 16; ++j) v[j] += __shfl_xor(v[j], st, 64);
        }
        float outv = v[0];
#pragma unroll
        for (int j = 1; j < 16; ++j) if ((lane & 15) == j) outv = v[j];
        if ((lane & 16) == 0) pout[tb + (lane & 15)] = outv;
    }
}

// ---------------------------------------------------------------------------
// kernel4: outputs. m_t = (sum partials + g_t*D)/D ; plus broadcasts/copies.
// ---------------------------------------------------------------------------
__global__ __launch_bounds__(256) void k4_outputs(
    const float* __restrict__ partials, const float* __restrict__ sum_ptr,
    const float* __restrict__ density, const float* __restrict__ s0,
    const float* __restrict__ mesh, const float* __restrict__ dec,
    const float* __restrict__ y0, float* __restrict__ out)
{
    int i = blockIdx.x * blockDim.x + threadIdx.x;
    const int NM = NB * TT;
    if (i < NM) {
        int b = i >> 11, t = i & (TT - 1);
        float h  = dec[b * TT + t];
        float hp = t ? dec[b * TT + t - 1] : y0[b];
        float g  = (h >= hp) ? 1.0f : -1.0f;
        float acc = 0.f;
#pragma unroll 8
        for (int k = 0; k < NBLK3 * 8; ++k)
            acc += partials[((size_t)(b * NBLK3 * 8 + k)) * TT + t];
        float D = sum_ptr[0];
        float m = (acc + g * D) / D;
        out[OUT_M + i] = m;
        out[OUT_BNORM + i] = 0.5f * m + 0.5f;
        return;
    }
    int j = i - NM;
    const int n1 = NB * N_MESH;
    if (j < n1) {
        out[OUT_DENSB + j] = density[j % N_MESH];
    } else if (j < 2 * n1) {
        int jj = j - n1;
        out[OUT_S0 + jj] = s0[jj];
    } else if (j < 4 * n1) {
        int jj = j - 2 * n1;
        out[OUT_MESHB + jj] = mesh[jj % (2 * N_MESH)];
    }
}

extern "C" void kernel_launch(void* const* d_in, const int* in_sizes, int n_in,
                              void* d_out, int out_size, void* d_ws, size_t ws_size,
                              hipStream_t stream) {
    const float* dec  = (const float*)d_in[1];
    const float* s0   = (const float*)d_in[2];
    const float* y0   = (const float*)d_in[3];
    const float* mesh = (const float*)d_in[4];
    const float* Win  = (const float*)d_in[5];
    const float* bin  = (const float*)d_in[6];
    const float* Wblk = (const float*)d_in[7];
    const float* bblk = (const float*)d_in[8];
    const float* Wout = (const float*)d_in[9];
    const float* bout = (const float*)d_in[10];
    float* out = (float*)d_out;
    float* ws  = (float*)d_ws;

    float* ws_density  = ws + WS_DENSITY;
    float* ws_sum      = ws + WS_SUM;
    float* ws_partials = ws + WS_PART;
    float* ws_P        = ws + WS_P;
    float* ws_Q        = ws + WS_Q;

    k1_mlp_scan1<<<MLP_NBLK + SCAN1_GRID, 256, 0, stream>>>(
        dec, y0, mesh, Win, bin, Wblk, bblk, Wout, bout,
        ws_density, ws_P, ws_Q);
    k2_phase2_sum<<<dim3(25, NB), 256, 0, stream>>>(
        s0, ws_P, ws_Q, ws_density, ws_sum);
    k3_phase3<<<SCAN1_GRID, 256, 0, stream>>>(
        dec, y0, mesh, ws_density, ws_P, ws_partials);
    {
        int total = NB * TT + NB * N_MESH * 4;   // 181216
        k4_outputs<<<(total + 255) / 256, 256, 0, stream>>>(
            ws_partials, ws_sum, ws_density, s0, mesh, dec, y0, out);
    }
}

// Round 6
// 106.971 us; speedup vs baseline: 1.5456x; 1.5456x over previous
//
#include <hip/hip_runtime.h>
#include <hip/hip_fp16.h>
#include <math.h>

#define N_MESH   5151
#define NB       8
#define TT       2048
#define HID      256
#define NLAYERS  3
#define NCHUNK   16
#define CHUNK    128           // TT / NCHUNK
#define TSTR     128           // table row stride (ushort), pow2
#define NPAD     6144          // 6 blocks * 1024
#define NBLK1    6             // scan n-blocks (1024 pts each, 4/thread)
#define NBLK3    6
#define SCAN1_GRID (NBLK1 * NB * NCHUNK)   // 768
#define MLP_ROWS 32
#define MLP_NBLK 161           // ceil(5151/32)

// ws layout (floats) -- total 2365440 floats = 9.46 MB
#define WS_DENSITY 0           // 5151
#define WS_SUM     5184        // 1
#define WS_PART    6144        // NB*NBLK3*8*TT = 786432 -> ends 792576
#define WS_PQ      792576      // NCHUNK*NB*NPAD*2 = 1572864 -> ends 2365440

// out layout (floats)
#define OUT_BNORM  0           // 16384
#define OUT_DENSB  16384       // 41208
#define OUT_M      57592       // 16384
#define OUT_S0     73976       // 41208
#define OUT_MESHB  115184      // 82416

#define SMEM_BYTES 34048

__device__ __forceinline__ float sigmoid_fast(float x) {
    float e = __expf(-x);
    return __builtin_amdgcn_rcpf(1.0f + e);
}

// Direction-resolved A-table (fp16), linear conflict-free build.
__device__ __forceinline__ void build_table(int tid, const float* hs2,
                                            float* sgv, unsigned short* tab)
{
    if (tid < CHUNK) sgv[tid] = (hs2[tid + 1] >= hs2[tid]) ? 1.0f : -1.0f;
#pragma unroll
    for (int k = 0; k < (CHUNK * TSTR) / 256; ++k) {
        int idx = tid + k * 256;
        int t = idx >> 7, g = idx & 127;
        float ht = hs2[t + 1];
        bool inc = (ht >= hs2[t]);
        float bx = ht * 1000.0f;
        float y = inc ? fmaf(-10.f, (float)g, bx) : fmaf(10.f, (float)g, -bx);
        float A = __builtin_amdgcn_rcpf(1.0f + __expf(y));
        tab[idx] = __half_as_ushort(__float2half(A));
    }
}

__device__ __forceinline__ float4 fma4s(float s, float4 w, float4 a) {
    a.x = fmaf(s, w.x, a.x); a.y = fmaf(s, w.y, a.y);
    a.z = fmaf(s, w.z, a.z); a.w = fmaf(s, w.w, a.w);
    return a;
}

// ---------------------------------------------------------------------------
// kernel1: blocks [0,161) = density MLP (long pole, first),
//          blocks [161,929) = scan phase1. Block-uniform branch.
// MLP: 32 rows/block, 8 rows/wave; lane owns cols {c0a..c0a+3, c0b..c0b+3};
// lane-halves split K (k<128 vs k>=128), cross-half shfl reduce per layer.
// W streamed from L2 (no LDS staging); h in LDS (broadcast b128 reads);
// NO barriers in the MLP path.
// ---------------------------------------------------------------------------
__global__ __launch_bounds__(256) void k1_mlp_scan1(
    const float* __restrict__ dec, const float* __restrict__ y0,
    const float* __restrict__ mesh, const float* __restrict__ Win,
    const float* __restrict__ bin,  const float* __restrict__ Wblk,
    const float* __restrict__ bblk, const float* __restrict__ Wout,
    const float* __restrict__ bout, float* __restrict__ ws_density,
    float2* __restrict__ PQ)
{
    __shared__ __align__(16) char smem[SMEM_BYTES];
    const int tid = threadIdx.x;

    if (blockIdx.x < MLP_NBLK) {
        // ------------------ density MLP ------------------
        float* hA = (float*)smem;                // [32][256] = 32 KB
        const int w    = tid >> 6;
        const int lane = tid & 63;
        const int half = lane >> 5;              // k-half
        const int l32  = lane & 31;
        const int c0a  = l32 * 4;                // cols c0a..c0a+3
        const int c0b  = c0a + 128;              // cols c0b..c0b+3
        const int r0   = w * 8;                  // wave-private rows r0..r0+7
        const int row0 = blockIdx.x * MLP_ROWS;
        const int khalf = half * 128;

        // input layer
        {
            float4 wiA0 = *(const float4*)&Win[c0a];
            float4 wiB0 = *(const float4*)&Win[c0b];
            float4 wiA1 = *(const float4*)&Win[HID + c0a];
            float4 wiB1 = *(const float4*)&Win[HID + c0b];
            float4 biA  = *(const float4*)&bin[c0a];
            float4 biB  = *(const float4*)&bin[c0b];
#pragma unroll
            for (int j = 0; j < 8; ++j) {
                int gr = row0 + r0 + j;
                float m0 = 0.f, m1 = 0.f;
                if (gr < N_MESH) { m0 = mesh[2 * gr]; m1 = mesh[2 * gr + 1]; }
                float4 ha, hb;
                ha.x = fmaxf(fmaf(m0, wiA0.x, fmaf(m1, wiA1.x, biA.x)), 0.f);
                ha.y = fmaxf(fmaf(m0, wiA0.y, fmaf(m1, wiA1.y, biA.y)), 0.f);
                ha.z = fmaxf(fmaf(m0, wiA0.z, fmaf(m1, wiA1.z, biA.z)), 0.f);
                ha.w = fmaxf(fmaf(m0, wiA0.w, fmaf(m1, wiA1.w, biA.w)), 0.f);
                hb.x = fmaxf(fmaf(m0, wiB0.x, fmaf(m1, wiB1.x, biB.x)), 0.f);
                hb.y = fmaxf(fmaf(m0, wiB0.y, fmaf(m1, wiB1.y, biB.y)), 0.f);
                hb.z = fmaxf(fmaf(m0, wiB0.z, fmaf(m1, wiB1.z, biB.z)), 0.f);
                hb.w = fmaxf(fmaf(m0, wiB0.w, fmaf(m1, wiB1.w, biB.w)), 0.f);
                *(float4*)&hA[(r0 + j) * HID + c0a] = ha;   // 2-way dup write ok
                *(float4*)&hA[(r0 + j) * HID + c0b] = hb;
            }
        }

        for (int L = 0; L < NLAYERS; ++L) {
            const float* W = Wblk + (size_t)L * HID * HID + (size_t)khalf * HID;
            float4 aA[8], aB[8];
#pragma unroll
            for (int j = 0; j < 8; ++j) {
                aA[j] = make_float4(0.f, 0.f, 0.f, 0.f);
                aB[j] = make_float4(0.f, 0.f, 0.f, 0.f);
            }
            for (int kk = 0; kk < 128; kk += 4) {     // 32 iterations
                float4 hr[8];
#pragma unroll
                for (int j = 0; j < 8; ++j)
                    hr[j] = *(const float4*)&hA[(r0 + j) * HID + khalf + kk];
#pragma unroll
                for (int i = 0; i < 4; ++i) {
                    const float* Wk = W + (size_t)(kk + i) * HID;
                    float4 wA = *(const float4*)&Wk[c0a];
                    float4 wB = *(const float4*)&Wk[c0b];
#pragma unroll
                    for (int j = 0; j < 8; ++j) {
                        float hx = (i == 0) ? hr[j].x : (i == 1) ? hr[j].y
                                 : (i == 2) ? hr[j].z : hr[j].w;
                        aA[j] = fma4s(hx, wA, aA[j]);
                        aB[j] = fma4s(hx, wB, aB[j]);
                    }
                }
            }
            // cross-half reduce + residual + relu, write back
            float4 bbA = *(const float4*)&bblk[L * HID + c0a];
            float4 bbB = *(const float4*)&bblk[L * HID + c0b];
#pragma unroll
            for (int j = 0; j < 8; ++j) {
                aA[j].x += __shfl_xor(aA[j].x, 32, 64);
                aA[j].y += __shfl_xor(aA[j].y, 32, 64);
                aA[j].z += __shfl_xor(aA[j].z, 32, 64);
                aA[j].w += __shfl_xor(aA[j].w, 32, 64);
                aB[j].x += __shfl_xor(aB[j].x, 32, 64);
                aB[j].y += __shfl_xor(aB[j].y, 32, 64);
                aB[j].z += __shfl_xor(aB[j].z, 32, 64);
                aB[j].w += __shfl_xor(aB[j].w, 32, 64);
                int r = r0 + j;
                float4 h = *(float4*)&hA[r * HID + c0a];
                h.x += fmaxf(aA[j].x + bbA.x, 0.f);
                h.y += fmaxf(aA[j].y + bbA.y, 0.f);
                h.z += fmaxf(aA[j].z + bbA.z, 0.f);
                h.w += fmaxf(aA[j].w + bbA.w, 0.f);
                *(float4*)&hA[r * HID + c0a] = h;
                float4 g = *(float4*)&hA[r * HID + c0b];
                g.x += fmaxf(aB[j].x + bbB.x, 0.f);
                g.y += fmaxf(aB[j].y + bbB.y, 0.f);
                g.z += fmaxf(aB[j].z + bbB.z, 0.f);
                g.w += fmaxf(aB[j].w + bbB.w, 0.f);
                *(float4*)&hA[r * HID + c0b] = g;
            }
        }

        // output layer + sigmoid (reduce over 32 lanes; halves duplicate)
        {
            float4 woA = *(const float4*)&Wout[c0a];
            float4 woB = *(const float4*)&Wout[c0b];
            float bo = bout[0];
#pragma unroll
            for (int j = 0; j < 8; ++j) {
                int r = r0 + j;
                float4 ha = *(const float4*)&hA[r * HID + c0a];
                float4 hb = *(const float4*)&hA[r * HID + c0b];
                float p = ha.x * woA.x + ha.y * woA.y + ha.z * woA.z + ha.w * woA.w
                        + hb.x * woB.x + hb.y * woB.y + hb.z * woB.z + hb.w * woB.w;
#pragma unroll
                for (int st = 1; st < 32; st <<= 1) p += __shfl_xor(p, st, 64);
                if (lane == 0) {
                    int gr = row0 + r;
                    if (gr < N_MESH) ws_density[gr] = sigmoid_fast(p + bo);
                }
            }
        }
    } else {
        // ------------------ scan phase 1 ------------------
        float* hs2 = (float*)smem;                             // CHUNK+1
        float* sgv = hs2 + 132;                                // CHUNK
        unsigned short* tab = (unsigned short*)(smem + 1056);  // CHUNK*TSTR

        const int sb = blockIdx.x - MLP_NBLK;
        const int nb = sb % NBLK1;
        const int rem = sb / NBLK1;
        const int b = rem & 7;
        const int c = rem >> 3;
        const int t0 = c * CHUNK;

        if (tid < CHUNK) hs2[tid + 1] = dec[b * TT + t0 + tid];
        if (tid == 0) hs2[0] = (c == 0) ? y0[b] : dec[b * TT + t0 - 1];
        __syncthreads();
        build_table(tid, hs2, sgv, tab);
        __syncthreads();

        int ga[4], gb[4];
#pragma unroll
        for (int q = 0; q < 4; ++q) {
            int n = nb * 1024 + q * 256 + tid;
            if (n < N_MESH) {
                gb[q] = (int)(mesh[2 * n]     * 100.0f + 0.5f);
                ga[q] = (int)(mesh[2 * n + 1] * 100.0f + 0.5f);
            } else { ga[q] = 0; gb[q] = 0; }
        }

        float P[4] = {1.f, 1.f, 1.f, 1.f};
        float R[4];
        float gprev = sgv[0];
#pragma unroll
        for (int q = 0; q < 4; ++q) R[q] = -gprev;

        for (int tb = 0; tb < CHUNK; tb += 16) {
#pragma unroll
            for (int j = 0; j < 16; ++j) {
                int t = tb + j;
                float sgt = sgv[t];
                float dl = gprev - sgt;      // 0 or +-2, wave-uniform
                gprev = sgt;
                bool inc = sgt > 0.0f;
                int base = t << 7;
#pragma unroll
                for (int q = 0; q < 4; ++q) {
                    int ig = inc ? ga[q] : gb[q];
                    float A = __half2float(__ushort_as_half(tab[base + ig]));
                    float r = R[q] + dl;
                    P[q] *= A;
                    R[q] = r * A;
                }
            }
        }
        size_t basew = ((size_t)(c * NB + b)) * NPAD;
#pragma unroll
        for (int q = 0; q < 4; ++q) {
            int n = nb * 1024 + q * 256 + tid;
            float2 v; v.x = P[q]; v.y = R[q] + gprev;
            PQ[basew + n] = v;
        }
    }
}

// ---------------------------------------------------------------------------
// kernel2: phase2. Prefetch all 16 (P,Q), then serial chain; boundary state
// written into the .x slot. Plus density sum (one extra block).
// ---------------------------------------------------------------------------
__global__ __launch_bounds__(256) void k2_phase2_sum(
    const float* __restrict__ s0_in, float* __restrict__ PQf,
    const float* __restrict__ density, float* __restrict__ sum_out)
{
    const int tid = threadIdx.x;
    if (blockIdx.x == 24) {
        if (blockIdx.y != 0) return;
        __shared__ float red[4];
        float p = 0.f;
        for (int i = tid; i < N_MESH; i += 256) p += density[i];
#pragma unroll
        for (int st = 1; st < 64; st <<= 1) p += __shfl_xor(p, st, 64);
        int lane = tid & 63, w = tid >> 6;
        if (lane == 0) red[w] = p;
        __syncthreads();
        if (tid == 0) sum_out[0] = red[0] + red[1] + red[2] + red[3];
        return;
    }
    const int n = blockIdx.x * 256 + tid;
    const int b = blockIdx.y;
    float2 v[NCHUNK];
    const float2* PQ = (const float2*)PQf;
#pragma unroll
    for (int c = 0; c < NCHUNK; ++c)
        v[c] = PQ[((size_t)(c * NB + b)) * NPAD + n];
    float s = (n < N_MESH) ? s0_in[b * N_MESH + n] : 0.f;
#pragma unroll
    for (int c = 0; c < NCHUNK; ++c) {
        size_t idx = ((size_t)(c * NB + b)) * NPAD + n;
        PQf[2 * idx] = s;                 // boundary state for chunk c
        s = fmaf(v[c].x, s, v[c].y);
    }
}

// ---------------------------------------------------------------------------
// kernel3: phase3 replay. z-form: z = (z+dl)*A; sign term added in k4.
// ---------------------------------------------------------------------------
__global__ __launch_bounds__(256) void k3_phase3(
    const float* __restrict__ dec, const float* __restrict__ y0,
    const float* __restrict__ mesh, const float* __restrict__ density,
    const float* __restrict__ PQf, float* __restrict__ partials)
{
    __shared__ __align__(16) char smem[SMEM_BYTES];
    float* hs2 = (float*)smem;
    float* sgv = hs2 + 132;
    unsigned short* tab = (unsigned short*)(smem + 1056);

    const int tid = threadIdx.x;
    const int bx = blockIdx.x;
    const int nb = bx % NBLK3;
    const int rem = bx / NBLK3;
    const int b = rem & 7;
    const int c = rem >> 3;
    const int t0 = c * CHUNK;
    const int lane = tid & 63, w = tid >> 6;

    if (tid < CHUNK) hs2[tid + 1] = dec[b * TT + t0 + tid];
    if (tid == 0) hs2[0] = (c == 0) ? y0[b] : dec[b * TT + t0 - 1];
    __syncthreads();
    build_table(tid, hs2, sgv, tab);
    __syncthreads();

    int ga[4], gb[4];
    float d[4], z[4];
    float gprev = sgv[0];
#pragma unroll
    for (int q = 0; q < 4; ++q) {
        int n = nb * 1024 + q * 256 + tid;
        float S = 0.f;
        if (n < N_MESH) {
            gb[q] = (int)(mesh[2 * n]     * 100.0f + 0.5f);
            ga[q] = (int)(mesh[2 * n + 1] * 100.0f + 0.5f);
            d[q]  = density[n];
            S = PQf[2 * (((size_t)(c * NB + b)) * NPAD + n)];
        } else { ga[q] = 0; gb[q] = 0; d[q] = 0.f; }
        z[q] = S - gprev;
    }

    float* pout = partials +
        ((size_t)((b * NBLK3 + nb) * 8 + w * 2 + (lane >> 5))) * TT + t0;

    for (int tb = 0; tb < CHUNK; tb += 16) {
        float v[16];
#pragma unroll
        for (int j = 0; j < 16; ++j) {
            int t = tb + j;
            float sgt = sgv[t];
            float dl = gprev - sgt;
            gprev = sgt;
            bool inc = sgt > 0.0f;
            int base = t << 7;
            float a0, a1;
#pragma unroll
            for (int q = 0; q < 4; ++q) {
                int ig = inc ? ga[q] : gb[q];
                float A = __half2float(__ushort_as_half(tab[base + ig]));
                z[q] = (z[q] + dl) * A;
            }
            a0 = d[0] * z[0];
            a1 = d[1] * z[1];
            a0 = fmaf(d[2], z[2], a0);
            a1 = fmaf(d[3], z[3], a1);
            v[j] = a0 + a1;
        }
#pragma unroll
        for (int st = 1; st < 32; st <<= 1) {
#pragma unroll
            for (int j = 0; j < 16; ++j) v[j] += __shfl_xor(v[j], st, 64);
        }
        float outv = v[0];
#pragma unroll
        for (int j = 1; j < 16; ++j) if ((lane & 15) == j) outv = v[j];
        if ((lane & 16) == 0) pout[tb + (lane & 15)] = outv;
    }
}

// ---------------------------------------------------------------------------
// kernel4: outputs. m_t = (sum partials + g_t*D)/D ; plus broadcasts/copies.
// ---------------------------------------------------------------------------
__global__ __launch_bounds__(256) void k4_outputs(
    const float* __restrict__ partials, const float* __restrict__ sum_ptr,
    const float* __restrict__ density, const float* __restrict__ s0,
    const float* __restrict__ mesh, const float* __restrict__ dec,
    const float* __restrict__ y0, float* __restrict__ out)
{
    int i = blockIdx.x * blockDim.x + threadIdx.x;
    const int NM = NB * TT;
    if (i < NM) {
        int b = i >> 11, t = i & (TT - 1);
        float h  = dec[b * TT + t];
        float hp = t ? dec[b * TT + t - 1] : y0[b];
        float g  = (h >= hp) ? 1.0f : -1.0f;
        float acc = 0.f;
#pragma unroll 8
        for (int k = 0; k < NBLK3 * 8; ++k)
            acc += partials[((size_t)(b * NBLK3 * 8 + k)) * TT + t];
        float D = sum_ptr[0];
        float m = (acc + g * D) / D;
        out[OUT_M + i] = m;
        out[OUT_BNORM + i] = 0.5f * m + 0.5f;
        return;
    }
    int j = i - NM;
    const int n1 = NB * N_MESH;
    if (j < n1) {
        out[OUT_DENSB + j] = density[j % N_MESH];
    } else if (j < 2 * n1) {
        int jj = j - n1;
        out[OUT_S0 + jj] = s0[jj];
    } else if (j < 4 * n1) {
        int jj = j - 2 * n1;
        out[OUT_MESHB + jj] = mesh[jj % (2 * N_MESH)];
    }
}

extern "C" void kernel_launch(void* const* d_in, const int* in_sizes, int n_in,
                              void* d_out, int out_size, void* d_ws, size_t ws_size,
                              hipStream_t stream) {
    const float* dec  = (const float*)d_in[1];
    const float* s0   = (const float*)d_in[2];
    const float* y0   = (const float*)d_in[3];
    const float* mesh = (const float*)d_in[4];
    const float* Win  = (const float*)d_in[5];
    const float* bin  = (const float*)d_in[6];
    const float* Wblk = (const float*)d_in[7];
    const float* bblk = (const float*)d_in[8];
    const float* Wout = (const float*)d_in[9];
    const float* bout = (const float*)d_in[10];
    float* out = (float*)d_out;
    float* ws  = (float*)d_ws;

    float* ws_density  = ws + WS_DENSITY;
    float* ws_sum      = ws + WS_SUM;
    float* ws_partials = ws + WS_PART;
    float* ws_pq       = ws + WS_PQ;

    k1_mlp_scan1<<<MLP_NBLK + SCAN1_GRID, 256, 0, stream>>>(
        dec, y0, mesh, Win, bin, Wblk, bblk, Wout, bout,
        ws_density, (float2*)ws_pq);
    k2_phase2_sum<<<dim3(25, NB), 256, 0, stream>>>(
        s0, ws_pq, ws_density, ws_sum);
    k3_phase3<<<SCAN1_GRID, 256, 0, stream>>>(
        dec, y0, mesh, ws_density, ws_pq, ws_partials);
    {
        int total = NB * TT + NB * N_MESH * 4;   // 181216
        k4_outputs<<<(total + 255) / 256, 256, 0, stream>>>(
            ws_partials, ws_sum, ws_density, s0, mesh, dec, y0, out);
    }
}